// Round 13
// baseline (1001.459 us; speedup 1.0000x reference)
//
#include <hip/hip_runtime.h>

#define DEVFN __device__ __forceinline__

typedef _Float16 f16x8 __attribute__((ext_vector_type(8)));
typedef float f32x4 __attribute__((ext_vector_type(4)));

static constexpr int T   = 8192;   // tokens (B*S)
static constexpr int D   = 1024;
static constexpr int E   = 8;
static constexpr int DFF = 4096;
static constexpr int NG  = E + 1;            // 8 experts + shared
static constexpr int RTOT = 3*T;             // 2T routed rows + T shared rows
static constexpr int MAXRT = (2*T)/256 + E + T/256;   // 64 + 8 + 32 = 104 (256-row tiles)

DEVFN unsigned short f2h_bits(float v){
  _Float16 h = (_Float16)v;           // RNE
  return __builtin_bit_cast(unsigned short, h);
}

DEVFN void gload_lds16(const void* g, void* l){
  __builtin_amdgcn_global_load_lds((const __attribute__((address_space(1))) void*)g,
                                   (__attribute__((address_space(3))) void*)l, 16, 0, 0);
}

// ---------------- prep: router (fp32 logits, top-2) + fused weight casts ----------------
// grid = 2048 x 256.  Each block: 4 router tokens (4 waves), then grid-stride cast of the
// 4 weight tensors (fp32 -> fp16).  Router is VALU-light, cast is BW-bound: they overlap.
__global__ __launch_bounds__(256) void prep_kernel(
    const float* __restrict__ x, const float* __restrict__ rw,
    unsigned short* __restrict__ xb,
    int* __restrict__ tok_e, float* __restrict__ tok_w, int* __restrict__ counts,
    const float* __restrict__ s0, const float* __restrict__ s1,
    const float* __restrict__ s2, const float* __restrict__ s3,
    unsigned short* __restrict__ d0, unsigned short* __restrict__ d1,
    unsigned short* __restrict__ d2, unsigned short* __restrict__ d3,
    int n0, int n1, int n2, int n3){
  // ---- router part ----
  const int lane = threadIdx.x & 63;
  const int t = blockIdx.x*4 + (threadIdx.x >> 6);
  const float4* xp = (const float4*)(x + (size_t)t*D);
  ushort4* xo = (ushort4*)(xb + (size_t)t*D);
  float acc[E];
#pragma unroll
  for (int e=0;e<E;e++) acc[e]=0.f;
#pragma unroll
  for (int i=0;i<4;i++){
    float4 xv = xp[lane + (i<<6)];
    ushort4 o; o.x=f2h_bits(xv.x); o.y=f2h_bits(xv.y); o.z=f2h_bits(xv.z); o.w=f2h_bits(xv.w);
    xo[lane + (i<<6)] = o;
#pragma unroll
    for (int e=0;e<E;e++){
      float4 wv = ((const float4*)(rw + e*D))[lane + (i<<6)];
      acc[e] = fmaf(xv.x,wv.x, fmaf(xv.y,wv.y, fmaf(xv.z,wv.z, fmaf(xv.w,wv.w, acc[e]))));
    }
  }
#pragma unroll
  for (int e=0;e<E;e++){
#pragma unroll
    for (int off=32; off>0; off>>=1) acc[e] += __shfl_xor(acc[e], off);
  }
  if (lane==0){
    float l0=-1e30f, l1=-1e30f; int e0=0, e1=0;
#pragma unroll
    for (int e=0;e<E;e++){
      float v = acc[e];
      if (v > l0){ l1=l0; e1=e0; l0=v; e0=e; }
      else if (v > l1){ l1=v; e1=e; }
    }
    float r   = expf(l1 - l0);          // p1/p0
    float inv = 1.f/(1.f + r);
    tok_e[2*t]   = e0; tok_e[2*t+1] = e1;
    tok_w[2*t]   = inv; tok_w[2*t+1] = r*inv;
    atomicAdd(&counts[e0], 1);
    atomicAdd(&counts[e1], 1);
  }
  // ---- cast part (grid-stride over 4 tensors, float4 units) ----
  int total = n0 + n1 + n2 + n3;
  for (int j = blockIdx.x*256 + threadIdx.x; j < total; j += gridDim.x*256){
    const float* sp; unsigned short* dp; int loc = j;
    if (loc < n0){ sp = s0; dp = d0; }
    else if ((loc -= n0) < n1){ sp = s1; dp = d1; }
    else if ((loc -= n1) < n2){ sp = s2; dp = d2; }
    else { loc -= n2; sp = s3; dp = d3; }
    float4 v = ((const float4*)sp)[loc];
    ushort4 o;
    o.x = f2h_bits(v.x); o.y = f2h_bits(v.y); o.z = f2h_bits(v.z); o.w = f2h_bits(v.w);
    ((ushort4*)dp)[loc] = o;
  }
}

// ---------------- scan: offsets + row-tile map (9 groups, 256-row tiles) ----------------
__global__ void scan_kernel(const int* __restrict__ counts, int* __restrict__ offs,
                            int* __restrict__ tile_g, int* __restrict__ tile_r0,
                            int* __restrict__ nrt){
  if (blockIdx.x==0 && threadIdx.x==0){
    int off=0, nt=0;
    for (int e=0;e<E;e++){
      offs[e]=off;
      int c = counts[e];
      int tiles = (c+255)>>8;
      for (int i=0;i<tiles;i++){ tile_g[nt]=e; tile_r0[nt]=off + (i<<8); nt++; }
      off += c;
    }
    offs[E] = off;                       // == 2T
    for (int i=0;i<T/256;i++){ tile_g[nt]=E; tile_r0[nt]=2*T + (i<<8); nt++; }
    offs[E+1] = 3*T;
    *nrt = nt;
  }
}

// ---------------- scatter: grouped row -> token; inverse map token -> grouped rows ----------------
__global__ __launch_bounds__(256) void scatter_kernel(const int* __restrict__ tok_e,
    const float* __restrict__ tok_w, const int* __restrict__ offs,
    int* __restrict__ fill, int* __restrict__ row_tok, float* __restrict__ row_w,
    int* __restrict__ inv2){
  int idx = blockIdx.x*256 + threadIdx.x;   // [0, 3T)
  if (idx < 2*T){
    int e = tok_e[idx];
    int pos = offs[e] + atomicAdd(&fill[e], 1);
    row_tok[pos] = idx >> 1;
    row_w[pos]   = tok_w[idx];
    inv2[idx]    = pos;                     // inv2[2*token + slot]
  } else {
    row_tok[idx] = idx - 2*T;
    row_w[idx]   = 1.0f;
  }
}

// ---- grouped GEMM, BM=256, BK=64, ring-2 LDS, r4/r9 8-phase schedule (best measured).
// MODE 0: FC,   BN=256, 2x4 waves -> wave tile 128x64 (8m x 4n), VMW(4), LDS 128 KB.
// MODE 1: PROJ, BN=128, 2x4 waves -> wave tile 128x32 (8m x 2n), VMW(3), LDS  96 KB.
//   BN=128 halves PROJ block time -> grid 832 blocks = 3.25 rounds (tail 8% vs 23%).
// Ledger (per iteration = 2 K-tiles, stages one half-tile per phase p1..p8):
//   p1 A(kt+1,0) | p2 B(kt+1,0)+VMW | p3 A(kt+1,1) | p4 B(kt+1,1)+VMW(or 0 if last)
//   p5 A(kt+2,0) | p6 B(kt+2,0)+VMW | p7 A(kt+2,1) | p8 B(kt+2,1)+VMW
//   Each counted VMW (4 for MODE0: half = 2A+2B loads; 3 for MODE1: 2A+1B) retires exactly
//   the half staged 3-4 phases earlier, one phase before any wave reads it (then barrier).
//   WAR: stage(kt+1,*) overwrites buf (kt-1)&1, last read 2+ barriers earlier.
template<int MODE>
DEVFN void gemm_core(
    const unsigned short* __restrict__ A, const unsigned short* __restrict__ Ball,
    unsigned short* __restrict__ O,
    const int K, const int N, const int CT,
    const int* __restrict__ tile_g, const int* __restrict__ tile_r0,
    const int* __restrict__ offs, const int* __restrict__ nrt,
    const int* __restrict__ row_tok)
{
  constexpr int BN  = MODE ? 128 : 256;
  constexpr int NFN = MODE ? 2 : 4;          // B frags per wave
  constexpr int NLB = MODE ? 1 : 2;          // B stage calls (loads/thread) per half-tile
  constexpr int BHT = BN*32;                 // shorts per B half-tile

  // T1: bijective XCD swizzle on linearized wg id (m204 form)
  const int nwg  = gridDim.x * gridDim.y;
  const int orig = blockIdx.y * gridDim.x + blockIdx.x;
  const int q8 = nwg >> 3, r8 = nwg & 7;
  const int xcd = orig & 7, pos = orig >> 3;
  const int wg = (xcd < r8 ? xcd*(q8+1) : r8*(q8+1) + (xcd-r8)*q8) + pos;
  const int rt = wg / CT, ct = wg - rt*CT;
  if (rt >= *nrt) return;

  const int g    = tile_g[rt];
  const int row0 = tile_r0[rt];
  const int row_end = offs[g+1];
  const unsigned short* Bp = Ball + (size_t)g * (size_t)N * (size_t)K;

  __shared__ __align__(16) unsigned short As[2*2*8192];  // 2buf x 2khalf x [256][32]
  __shared__ __align__(16) unsigned short Bs[2*2*BHT];   // 2buf x 2khalf x [BN][32]

  const int tid  = threadIdx.x;
  const int lane = tid & 63;
  const int wave = tid >> 6;

  // --- staging maps (0-conflict swizzle family, verified r1-r11)
  const unsigned short* aS[2];
  int ldstA[2];
#pragma unroll
  for (int c=0;c<2;c++){
    int s_lin = (c<<9) + tid;
    int rr = s_lin >> 2;
    int qg = (s_lin & 3) ^ ((rr >> 1) & 3);
    int ar = (MODE==0) ? row_tok[row0 + rr] : (row0 + rr);  // row_tok fully populated on [0,3T)
    aS[c] = A + (size_t)ar*K + qg*8;
    ldstA[c] = ((c<<9) + (wave<<6))*8;
  }
  const unsigned short* bS[NLB];
  int ldstB[NLB];
#pragma unroll
  for (int c=0;c<NLB;c++){
    int s_lin = (c<<9) + tid;
    int rr = s_lin >> 2;
    int qg = (s_lin & 3) ^ ((rr >> 1) & 3);
    bS[c] = Bp + (size_t)(ct*BN + rr)*K + qg*8;
    ldstB[c] = ((c<<9) + (wave<<6))*8;
  }

#define STAGE_A(KT,KS) { _Pragma("unroll") for (int c=0;c<2;c++) \
    gload_lds16(aS[c] + (KT)*64 + (KS)*32, As + ((((KT)&1)*2+(KS))<<13) + ldstA[c]); }
#define STAGE_B(KT,KS) { _Pragma("unroll") for (int c=0;c<NLB;c++) \
    gload_lds16(bS[c] + (KT)*64 + (KS)*32, Bs + (((KT)&1)*2+(KS))*BHT + ldstB[c]); }

  // --- fragment read offsets (swizzle matches staging)
  const int wm = wave >> 2, wn = wave & 3;   // 2x4 waves
  const int q16g = lane >> 4;
  int aoff[8], boff[NFN];
#pragma unroll
  for (int m=0;m<8;m++){
    int r = (wm<<7) + (m<<4) + (lane&15);
    aoff[m] = (r<<5) + ((q16g ^ ((r>>1)&3))<<3);
  }
#pragma unroll
  for (int n=0;n<NFN;n++){
    int r = wn*(BN/4) + (n<<4) + (lane&15);
    boff[n] = (r<<5) + ((q16g ^ ((r>>1)&3))<<3);
  }

#define BARS { __builtin_amdgcn_s_barrier(); __builtin_amdgcn_sched_barrier(0); }
#define VMW(NN) asm volatile("s_waitcnt vmcnt(" #NN ")" ::: "memory");
#define VMWC { if constexpr (MODE==0) { VMW(4) } else { VMW(3) } }
#define DSA(BUF,KS,MQ) { const unsigned short* hb = As + (((BUF)*2+(KS))<<13); \
    _Pragma("unroll") for (int m=0;m<4;m++) af[m] = *(const f16x8*)(hb + aoff[(MQ)*4+m]); }
#define DSB(BUF,KS) { const unsigned short* hb = Bs + ((BUF)*2+(KS))*BHT; \
    _Pragma("unroll") for (int n=0;n<NFN;n++) bf[n] = *(const f16x8*)(hb + boff[n]); }
#define MFMAC(MQ) { __builtin_amdgcn_s_setprio(1); \
    _Pragma("unroll") for (int m=0;m<4;m++) \
    _Pragma("unroll") for (int n=0;n<NFN;n++) \
      acc[(MQ)*4+m][n] = __builtin_amdgcn_mfma_f32_16x16x32_f16(af[m], bf[n], acc[(MQ)*4+m][n], 0, 0, 0); \
    __builtin_amdgcn_s_setprio(0); }

  f32x4 acc[8][NFN] = {};
  const int nkt = K >> 6;                    // 64-wide K tiles
  const int ni  = nkt >> 1;

  // prologue: stage K-tile 0 (A0,B0,A1,B1); retire half 0; barrier
  STAGE_A(0,0); STAGE_B(0,0); STAGE_A(0,1); STAGE_B(0,1);
  VMWC; BARS;

  f16x8 af[4], bf[NFN];
  for (int i=0;i<ni;++i){
    const int kt = i<<1;
    const bool last = (i == ni-1);
    // ---- K-tile kt (buf0), stage K-tile kt+1 -> buf1
    DSB(0,0); DSA(0,0,0); STAGE_A(kt+1,0);              BARS; MFMAC(0); BARS;   // p1
    DSA(0,0,1);           STAGE_B(kt+1,0); VMWC;        BARS; MFMAC(1); BARS;   // p2
    DSB(0,1); DSA(0,1,0); STAGE_A(kt+1,1);              BARS; MFMAC(0); BARS;   // p3
    DSA(0,1,1);           STAGE_B(kt+1,1);                                      // p4
    if (last) { VMW(0); } else { VMWC; }
    BARS; MFMAC(1); BARS;
    // ---- K-tile kt+1 (buf1), stage K-tile kt+2 -> buf0
    DSB(1,0); DSA(1,0,0); if (!last) STAGE_A(kt+2,0);   BARS; MFMAC(0); BARS;   // p5
    DSA(1,0,1);           if (!last) STAGE_B(kt+2,0);
    VMWC;                                               BARS; MFMAC(1); BARS;   // p6
    DSB(1,1); DSA(1,1,0); if (!last) STAGE_A(kt+2,1);   BARS; MFMAC(0); BARS;   // p7
    DSA(1,1,1);           if (!last) STAGE_B(kt+2,1);
    VMWC;                                               BARS; MFMAC(1); BARS;   // p8
  }

  // --- epilogue: C row = (lane>>4)*4 + q, col = lane&15 within each 16x16 fragment
  const int lcol = lane & 15;
  const int lrow = (lane >> 4) << 2;
#pragma unroll
  for (int m=0;m<8;m++){
#pragma unroll
    for (int q=0;q<4;q++){
      const int grow = row0 + (wm<<7) + (m<<4) + lrow + q;
      if (grow >= row_end) continue;           // padded tile rows
#pragma unroll
      for (int n=0;n<NFN;n++){
        const int col = ct*BN + wn*(BN/4) + (n<<4) + lcol;
        float v = acc[m][n][q];
        if constexpr (MODE==0) v = (v > 0.f) ? v*v : 0.f;   // relu(x)^2
        O[(size_t)grow*N + col] = f2h_bits(v);
      }
    }
  }
#undef STAGE_A
#undef STAGE_B
#undef BARS
#undef VMW
#undef VMWC
#undef DSA
#undef DSB
#undef MFMAC
}

// distinct symbols so rocprof separates the two GEMMs
__global__ __launch_bounds__(512, 2) void gemm_fc(
    const unsigned short* __restrict__ A, const unsigned short* __restrict__ Ball,
    unsigned short* __restrict__ O, const int K, const int N, const int CT,
    const int* __restrict__ tile_g, const int* __restrict__ tile_r0,
    const int* __restrict__ offs, const int* __restrict__ nrt,
    const int* __restrict__ row_tok){
  gemm_core<0>(A, Ball, O, K, N, CT, tile_g, tile_r0, offs, nrt, row_tok);
}
__global__ __launch_bounds__(512, 2) void gemm_proj(
    const unsigned short* __restrict__ A, const unsigned short* __restrict__ Ball,
    unsigned short* __restrict__ O, const int K, const int N, const int CT,
    const int* __restrict__ tile_g, const int* __restrict__ tile_r0,
    const int* __restrict__ offs, const int* __restrict__ nrt,
    const int* __restrict__ row_tok){
  gemm_core<1>(A, Ball, O, K, N, CT, tile_g, tile_r0, offs, nrt, row_tok);
}

// ---------------- combine: out[t] = w0*y[p0] + w1*y[p1] + y[shared_t] ----------------
__global__ __launch_bounds__(256) void combine_kernel(const unsigned short* __restrict__ y,
    const int* __restrict__ inv2, const float* __restrict__ row_w, float* __restrict__ out){
  int gid = blockIdx.x*256 + threadIdx.x;    // T*128 threads, 8 cols each
  int t = gid >> 7, c = gid & 127;
  int p0 = inv2[2*t], p1 = inv2[2*t+1];
  float w0 = row_w[p0], w1 = row_w[p1];
  f16x8 v0 = *(const f16x8*)(y + (size_t)p0*D      + c*8);
  f16x8 v1 = *(const f16x8*)(y + (size_t)p1*D      + c*8);
  f16x8 v2 = *(const f16x8*)(y + (size_t)(2*T+t)*D + c*8);
  float4 o0, o1;
  float r[8];
#pragma unroll
  for (int j=0;j<8;j++)
    r[j] = fmaf(w0, (float)v0[j], fmaf(w1, (float)v1[j], (float)v2[j]));
  o0.x=r[0]; o0.y=r[1]; o0.z=r[2]; o0.w=r[3];
  o1.x=r[4]; o1.y=r[5]; o1.z=r[6]; o1.w=r[7];
  float4* op = (float4*)(out + (size_t)t*D + c*8);
  op[0] = o0; op[1] = o1;
}

// ---------------- host launcher ----------------
extern "C" void kernel_launch(void* const* d_in, const int* in_sizes, int n_in,
                              void* d_out, int out_size, void* d_ws, size_t ws_size,
                              hipStream_t stream){
  const float* x     = (const float*)d_in[0];
  const float* rw    = (const float*)d_in[1];
  const float* wfc   = (const float*)d_in[2];
  const float* wproj = (const float*)d_in[3];
  const float* sfc   = (const float*)d_in[4];
  const float* sproj = (const float*)d_in[5];
  float* out = (float*)d_out;

  char* ws = (char*)d_ws;
  size_t off = 0;
  auto alloc = [&](size_t bytes)->void*{
    void* p = ws + off; off += (bytes + 255) & ~(size_t)255; return p;
  };
  unsigned short* xb    = (unsigned short*)alloc((size_t)T*D*2);
  unsigned short* wall  = (unsigned short*)alloc((size_t)NG*DFF*D*2);  // experts 0..7 then shared
  unsigned short* wpall = (unsigned short*)alloc((size_t)NG*D*DFF*2);
  unsigned short* h     = (unsigned short*)alloc((size_t)RTOT*DFF*2);
  int*   tok_e   = (int*)  alloc((size_t)T*2*4);
  float* tok_w   = (float*)alloc((size_t)T*2*4);
  int*   row_tok = (int*)  alloc((size_t)RTOT*4);
  float* row_w   = (float*)alloc((size_t)RTOT*4);
  int*   inv2    = (int*)  alloc((size_t)2*T*4);
  int* counts  = (int*)alloc(E*4);
  int* fill    = (int*)alloc(E*4);
  int* offs    = (int*)alloc((E+2)*4);
  int* nrt     = (int*)alloc(4);
  int* tile_g  = (int*)alloc(MAXRT*4);
  int* tile_r0 = (int*)alloc(MAXRT*4);
  if (off > ws_size) return;   // visible failure if workspace too small

  // y [3T][D] f16 aliases wall: FC (last reader of wall) completes before PROJ writes y.
  unsigned short* y = wall;    // 50 MB needed, 75 MB available

  hipMemsetAsync(counts, 0, E*4, stream);
  hipMemsetAsync(fill,   0, E*4, stream);

  // router + all weight casts in one dispatch
  prep_kernel<<<T/4, 256, 0, stream>>>(
      x, rw, xb, tok_e, tok_w, counts,
      wfc, sfc, wproj, sproj,
      wall, wall + (size_t)E*DFF*D, wpall, wpall + (size_t)E*D*DFF,
      E*DFF*D/4, DFF*D/4, E*D*DFF/4, D*DFF/4);

  scan_kernel   <<<1,   64,  0, stream>>>(counts, offs, tile_g, tile_r0, nrt);
  scatter_kernel<<<RTOT/256, 256, 0, stream>>>(tok_e, tok_w, offs, fill, row_tok, row_w, inv2);

  // FC: h = relu(x @ w_fc^T)^2 for all grouped rows (incl. shared)   [BN=256]
  gemm_fc  <<<dim3(DFF/256, MAXRT), 512, 0, stream>>>(
      xb, wall, h, D, DFF, DFF/256, tile_g, tile_r0, offs, nrt, row_tok);
  // PROJ: y = h @ w_proj^T (raw, unweighted)                          [BN=128]
  gemm_proj<<<dim3(D/128, MAXRT), 512, 0, stream>>>(
      h, wpall, y, DFF, D, D/128, tile_g, tile_r0, offs, nrt, row_tok);
  // combine: weighted sum per token
  combine_kernel<<<(T*128)/256, 256, 0, stream>>>(y, inv2, row_w, out);
}

// Round 14
// 840.661 us; speedup vs baseline: 1.1913x; 1.1913x over previous
//
#include <hip/hip_runtime.h>

#define DEVFN __device__ __forceinline__

typedef _Float16 f16x8 __attribute__((ext_vector_type(8)));
typedef float f32x4 __attribute__((ext_vector_type(4)));

static constexpr int T   = 8192;   // tokens (B*S)
static constexpr int D   = 1024;
static constexpr int E   = 8;
static constexpr int DFF = 4096;
static constexpr int NG  = E + 1;            // 8 experts + shared
static constexpr int RTOT = 3*T;             // 2T routed rows + T shared rows
static constexpr int MAXRT = (2*T)/256 + E + T/256;   // 64 + 8 + 32 = 104 (256-row tiles)

DEVFN unsigned short f2h_bits(float v){
  _Float16 h = (_Float16)v;           // RNE
  return __builtin_bit_cast(unsigned short, h);
}

DEVFN void gload_lds16(const void* g, void* l){
  __builtin_amdgcn_global_load_lds((const __attribute__((address_space(1))) void*)g,
                                   (__attribute__((address_space(3))) void*)l, 16, 0, 0);
}

// ---------------- prep: router (fp32 logits, top-2) + fused weight casts ----------------
__global__ __launch_bounds__(256) void prep_kernel(
    const float* __restrict__ x, const float* __restrict__ rw,
    unsigned short* __restrict__ xb,
    int* __restrict__ tok_e, float* __restrict__ tok_w, int* __restrict__ counts,
    const float* __restrict__ s0, const float* __restrict__ s1,
    const float* __restrict__ s2, const float* __restrict__ s3,
    unsigned short* __restrict__ d0, unsigned short* __restrict__ d1,
    unsigned short* __restrict__ d2, unsigned short* __restrict__ d3,
    int n0, int n1, int n2, int n3){
  // ---- router part ----
  const int lane = threadIdx.x & 63;
  const int t = blockIdx.x*4 + (threadIdx.x >> 6);
  const float4* xp = (const float4*)(x + (size_t)t*D);
  ushort4* xo = (ushort4*)(xb + (size_t)t*D);
  float acc[E];
#pragma unroll
  for (int e=0;e<E;e++) acc[e]=0.f;
#pragma unroll
  for (int i=0;i<4;i++){
    float4 xv = xp[lane + (i<<6)];
    ushort4 o; o.x=f2h_bits(xv.x); o.y=f2h_bits(xv.y); o.z=f2h_bits(xv.z); o.w=f2h_bits(xv.w);
    xo[lane + (i<<6)] = o;
#pragma unroll
    for (int e=0;e<E;e++){
      float4 wv = ((const float4*)(rw + e*D))[lane + (i<<6)];
      acc[e] = fmaf(xv.x,wv.x, fmaf(xv.y,wv.y, fmaf(xv.z,wv.z, fmaf(xv.w,wv.w, acc[e]))));
    }
  }
#pragma unroll
  for (int e=0;e<E;e++){
#pragma unroll
    for (int off=32; off>0; off>>=1) acc[e] += __shfl_xor(acc[e], off);
  }
  if (lane==0){
    float l0=-1e30f, l1=-1e30f; int e0=0, e1=0;
#pragma unroll
    for (int e=0;e<E;e++){
      float v = acc[e];
      if (v > l0){ l1=l0; e1=e0; l0=v; e0=e; }
      else if (v > l1){ l1=v; e1=e; }
    }
    float r   = expf(l1 - l0);          // p1/p0
    float inv = 1.f/(1.f + r);
    tok_e[2*t]   = e0; tok_e[2*t+1] = e1;
    tok_w[2*t]   = inv; tok_w[2*t+1] = r*inv;
    atomicAdd(&counts[e0], 1);
    atomicAdd(&counts[e1], 1);
  }
  // ---- cast part (grid-stride over 4 tensors, float4 units) ----
  int total = n0 + n1 + n2 + n3;
  for (int j = blockIdx.x*256 + threadIdx.x; j < total; j += gridDim.x*256){
    const float* sp; unsigned short* dp; int loc = j;
    if (loc < n0){ sp = s0; dp = d0; }
    else if ((loc -= n0) < n1){ sp = s1; dp = d1; }
    else if ((loc -= n1) < n2){ sp = s2; dp = d2; }
    else { loc -= n2; sp = s3; dp = d3; }
    float4 v = ((const float4*)sp)[loc];
    ushort4 o;
    o.x = f2h_bits(v.x); o.y = f2h_bits(v.y); o.z = f2h_bits(v.z); o.w = f2h_bits(v.w);
    ((ushort4*)dp)[loc] = o;
  }
}

// ---------------- scan: offsets + row-tile map (9 groups, 256-row tiles) ----------------
__global__ void scan_kernel(const int* __restrict__ counts, int* __restrict__ offs,
                            int* __restrict__ tile_g, int* __restrict__ tile_r0,
                            int* __restrict__ nrt){
  if (blockIdx.x==0 && threadIdx.x==0){
    int off=0, nt=0;
    for (int e=0;e<E;e++){
      offs[e]=off;
      int c = counts[e];
      int tiles = (c+255)>>8;
      for (int i=0;i<tiles;i++){ tile_g[nt]=e; tile_r0[nt]=off + (i<<8); nt++; }
      off += c;
    }
    offs[E] = off;                       // == 2T
    for (int i=0;i<T/256;i++){ tile_g[nt]=E; tile_r0[nt]=2*T + (i<<8); nt++; }
    offs[E+1] = 3*T;
    *nrt = nt;
  }
}

// ---------------- scatter: grouped row -> token; inverse map token -> grouped rows ----------------
__global__ __launch_bounds__(256) void scatter_kernel(const int* __restrict__ tok_e,
    const float* __restrict__ tok_w, const int* __restrict__ offs,
    int* __restrict__ fill, int* __restrict__ row_tok, float* __restrict__ row_w,
    int* __restrict__ inv2){
  int idx = blockIdx.x*256 + threadIdx.x;   // [0, 3T)
  if (idx < 2*T){
    int e = tok_e[idx];
    int pos = offs[e] + atomicAdd(&fill[e], 1);
    row_tok[pos] = idx >> 1;
    row_w[pos]   = tok_w[idx];
    inv2[idx]    = pos;                     // inv2[2*token + slot]
  } else {
    row_tok[idx] = idx - 2*T;
    row_w[idx]   = 1.0f;
  }
}

// ---- grouped GEMM, 256x256 tile, BK=64, ring-2 LDS (128 KB), r4/r9 8-phase schedule
//      (best-measured across r4-r12: ~265-275 us per dispatch, MfmaUtil ~34%).
//      Per iteration (2 K-tiles), 8 phases; each phase: {ds_read frags || stage 1 half-tile
//      [|| counted VMW(4)] -> bar -> 16-MFMA cluster (setprio) -> bar}.  Only the last
//      K-tile drains vmcnt to 0.  Swizzle family verified 0-conflict (r1-r12).
// MODE 0: FC (A gathered via row_tok, relu^2 -> h).  MODE 1: PROJ (A contiguous, raw -> y).
template<int MODE>
DEVFN void gemm_core(
    const unsigned short* __restrict__ A, const unsigned short* __restrict__ Ball,
    unsigned short* __restrict__ O,
    const int K, const int N, const int CT,
    const int* __restrict__ tile_g, const int* __restrict__ tile_r0,
    const int* __restrict__ offs, const int* __restrict__ nrt,
    const int* __restrict__ row_tok)
{
  // T1: bijective XCD swizzle on linearized wg id (m204 form)
  const int nwg  = gridDim.x * gridDim.y;
  const int orig = blockIdx.y * gridDim.x + blockIdx.x;
  const int q8 = nwg >> 3, r8 = nwg & 7;
  const int xcd = orig & 7, pos = orig >> 3;
  const int wg = (xcd < r8 ? xcd*(q8+1) : r8*(q8+1) + (xcd-r8)*q8) + pos;
  const int rt = wg / CT, ct = wg - rt*CT;
  if (rt >= *nrt) return;

  const int g    = tile_g[rt];
  const int row0 = tile_r0[rt];
  const int row_end = offs[g+1];
  const unsigned short* Bp = Ball + (size_t)g * (size_t)N * (size_t)K;

  // HT(buf,ks) base = (buf*2+ks)*8192 shorts; each HT = [256 rows][4 x 16B chunks] (k-half)
  __shared__ __align__(16) unsigned short As[2*2*8192];
  __shared__ __align__(16) unsigned short Bs[2*2*8192];

  const int tid  = threadIdx.x;
  const int lane = tid & 63;
  const int wave = tid >> 6;

  // --- staging map: slot s = c*512+tid; row rr = s>>2; local chunk = s&3;
  //     inverse-swizzled global chunk qg = (s&3) ^ ((rr>>1)&3)   (0-conflict, r1-r12)
  const unsigned short* aS[2];
  const unsigned short* bS[2];
  int ldst[2];
#pragma unroll
  for (int c=0;c<2;c++){
    int s  = (c<<9) + tid;
    int rr = s >> 2;
    int qg = (s & 3) ^ ((rr >> 1) & 3);
    int ar = (MODE==0) ? row_tok[row0 + rr] : (row0 + rr);  // row_tok valid on [0,3T)
    aS[c] = A  + (size_t)ar*K + qg*8;
    bS[c] = Bp + (size_t)((ct<<8) + rr)*K + qg*8;
    ldst[c] = ((c<<9) + (wave<<6))*8;        // wave-uniform LDS base (lane*16B implicit)
  }

#define STAGE_A(KT,KS) { _Pragma("unroll") for (int c=0;c<2;c++) \
    gload_lds16(aS[c] + (KT)*64 + (KS)*32, As + ((((KT)&1)*2+(KS))<<13) + ldst[c]); }
#define STAGE_B(KT,KS) { _Pragma("unroll") for (int c=0;c<2;c++) \
    gload_lds16(bS[c] + (KT)*64 + (KS)*32, Bs + ((((KT)&1)*2+(KS))<<13) + ldst[c]); }

  // --- fragment read offsets within a half-tile [256][32] shorts (swizzle matches staging)
  const int wm = wave >> 2, wn = wave & 3;   // 2x4 waves, per-wave output 128 x 64
  const int q16g = lane >> 4;
  int aoff[8], boff[4];
#pragma unroll
  for (int m=0;m<8;m++){
    int r = (wm<<7) + (m<<4) + (lane&15);
    aoff[m] = (r<<5) + ((q16g ^ ((r>>1)&3))<<3);
  }
#pragma unroll
  for (int n=0;n<4;n++){
    int r = (wn<<6) + (n<<4) + (lane&15);
    boff[n] = (r<<5) + ((q16g ^ ((r>>1)&3))<<3);
  }

#define BARS { __builtin_amdgcn_s_barrier(); __builtin_amdgcn_sched_barrier(0); }
#define VMW(NN) asm volatile("s_waitcnt vmcnt(" #NN ")" ::: "memory");
#define DSA(BUF,KS,MQ) { const unsigned short* hb = As + (((BUF)*2+(KS))<<13); \
    _Pragma("unroll") for (int m=0;m<4;m++) af[m] = *(const f16x8*)(hb + aoff[(MQ)*4+m]); }
#define DSB(BUF,KS) { const unsigned short* hb = Bs + (((BUF)*2+(KS))<<13); \
    _Pragma("unroll") for (int n=0;n<4;n++) bf[n] = *(const f16x8*)(hb + boff[n]); }
#define MFMA16(MQ) { __builtin_amdgcn_s_setprio(1); \
    _Pragma("unroll") for (int m=0;m<4;m++) \
    _Pragma("unroll") for (int n=0;n<4;n++) \
      acc[(MQ)*4+m][n] = __builtin_amdgcn_mfma_f32_16x16x32_f16(af[m], bf[n], acc[(MQ)*4+m][n], 0, 0, 0); \
    __builtin_amdgcn_s_setprio(0); }

  f32x4 acc[8][4] = {};
  const int nkt = K >> 6;                    // 64-wide K tiles (16 FC / 64 PROJ)
  const int ni  = nkt >> 1;

  // prologue: stage K-tile 0 (A0,B0,A1,B1 = 8 loads); retire half 0; barrier
  STAGE_A(0,0); STAGE_B(0,0); STAGE_A(0,1); STAGE_B(0,1);
  VMW(4); BARS;

  f16x8 af[4], bf[4];
  for (int i=0;i<ni;++i){
    const int kt = i<<1;
    const bool last = (i == ni-1);
    // ---- K-tile kt (buf0), stage K-tile kt+1 -> buf1
    DSB(0,0); DSA(0,0,0); STAGE_A(kt+1,0);              BARS; MFMA16(0); BARS;  // p1
    DSA(0,0,1);           STAGE_B(kt+1,0); VMW(4);      BARS; MFMA16(1); BARS;  // p2
    DSB(0,1); DSA(0,1,0); STAGE_A(kt+1,1);              BARS; MFMA16(0); BARS;  // p3
    DSA(0,1,1);           STAGE_B(kt+1,1);                                      // p4
    if (last) { VMW(0); } else { VMW(4); }
    BARS; MFMA16(1); BARS;
    // ---- K-tile kt+1 (buf1), stage K-tile kt+2 -> buf0
    DSB(1,0); DSA(1,0,0); if (!last) STAGE_A(kt+2,0);   BARS; MFMA16(0); BARS;  // p5
    DSA(1,0,1);           if (!last) STAGE_B(kt+2,0);
    VMW(4);                                             BARS; MFMA16(1); BARS;  // p6
    DSB(1,1); DSA(1,1,0); if (!last) STAGE_A(kt+2,1);   BARS; MFMA16(0); BARS;  // p7
    DSA(1,1,1);           if (!last) STAGE_B(kt+2,1);
    VMW(4);                                             BARS; MFMA16(1); BARS;  // p8
  }

  // --- epilogue: C row = (lane>>4)*4 + q, col = lane&15 within each 16x16 fragment
  const int lcol = lane & 15;
  const int lrow = (lane >> 4) << 2;
#pragma unroll
  for (int m=0;m<8;m++){
#pragma unroll
    for (int q=0;q<4;q++){
      const int grow = row0 + (wm<<7) + (m<<4) + lrow + q;
      if (grow >= row_end) continue;           // padded tile rows
#pragma unroll
      for (int n=0;n<4;n++){
        const int col = (ct<<8) + (wn<<6) + (n<<4) + lcol;
        float v = acc[m][n][q];
        if constexpr (MODE==0) v = (v > 0.f) ? v*v : 0.f;   // relu(x)^2
        O[(size_t)grow*N + col] = f2h_bits(v);
      }
    }
  }
#undef STAGE_A
#undef STAGE_B
#undef BARS
#undef VMW
#undef DSA
#undef DSB
#undef MFMA16
}

// distinct symbols so rocprof separates the two GEMMs
__global__ __launch_bounds__(512, 2) void gemm_fc(
    const unsigned short* __restrict__ A, const unsigned short* __restrict__ Ball,
    unsigned short* __restrict__ O, const int K, const int N, const int CT,
    const int* __restrict__ tile_g, const int* __restrict__ tile_r0,
    const int* __restrict__ offs, const int* __restrict__ nrt,
    const int* __restrict__ row_tok){
  gemm_core<0>(A, Ball, O, K, N, CT, tile_g, tile_r0, offs, nrt, row_tok);
}
__global__ __launch_bounds__(512, 2) void gemm_proj(
    const unsigned short* __restrict__ A, const unsigned short* __restrict__ Ball,
    unsigned short* __restrict__ O, const int K, const int N, const int CT,
    const int* __restrict__ tile_g, const int* __restrict__ tile_r0,
    const int* __restrict__ offs, const int* __restrict__ nrt,
    const int* __restrict__ row_tok){
  gemm_core<1>(A, Ball, O, K, N, CT, tile_g, tile_r0, offs, nrt, row_tok);
}

// ---------------- combine: out[t] = w0*y[p0] + w1*y[p1] + y[shared_t] ----------------
__global__ __launch_bounds__(256) void combine_kernel(const unsigned short* __restrict__ y,
    const int* __restrict__ inv2, const float* __restrict__ row_w, float* __restrict__ out){
  int gid = blockIdx.x*256 + threadIdx.x;    // T*128 threads, 8 cols each
  int t = gid >> 7, c = gid & 127;
  int p0 = inv2[2*t], p1 = inv2[2*t+1];
  float w0 = row_w[p0], w1 = row_w[p1];
  f16x8 v0 = *(const f16x8*)(y + (size_t)p0*D      + c*8);
  f16x8 v1 = *(const f16x8*)(y + (size_t)p1*D      + c*8);
  f16x8 v2 = *(const f16x8*)(y + (size_t)(2*T+t)*D + c*8);
  float4 o0, o1;
  float r[8];
#pragma unroll
  for (int j=0;j<8;j++)
    r[j] = fmaf(w0, (float)v0[j], fmaf(w1, (float)v1[j], (float)v2[j]));
  o0.x=r[0]; o0.y=r[1]; o0.z=r[2]; o0.w=r[3];
  o1.x=r[4]; o1.y=r[5]; o1.z=r[6]; o1.w=r[7];
  float4* op = (float4*)(out + (size_t)t*D + c*8);
  op[0] = o0; op[1] = o1;
}

// ---------------- host launcher ----------------
extern "C" void kernel_launch(void* const* d_in, const int* in_sizes, int n_in,
                              void* d_out, int out_size, void* d_ws, size_t ws_size,
                              hipStream_t stream){
  const float* x     = (const float*)d_in[0];
  const float* rw    = (const float*)d_in[1];
  const float* wfc   = (const float*)d_in[2];
  const float* wproj = (const float*)d_in[3];
  const float* sfc   = (const float*)d_in[4];
  const float* sproj = (const float*)d_in[5];
  float* out = (float*)d_out;

  char* ws = (char*)d_ws;
  size_t off = 0;
  auto alloc = [&](size_t bytes)->void*{
    void* p = ws + off; off += (bytes + 255) & ~(size_t)255; return p;
  };
  unsigned short* xb    = (unsigned short*)alloc((size_t)T*D*2);
  unsigned short* wall  = (unsigned short*)alloc((size_t)NG*DFF*D*2);  // experts 0..7 then shared
  unsigned short* wpall = (unsigned short*)alloc((size_t)NG*D*DFF*2);
  unsigned short* h     = (unsigned short*)alloc((size_t)RTOT*DFF*2);
  int*   tok_e   = (int*)  alloc((size_t)T*2*4);
  float* tok_w   = (float*)alloc((size_t)T*2*4);
  int*   row_tok = (int*)  alloc((size_t)RTOT*4);
  float* row_w   = (float*)alloc((size_t)RTOT*4);
  int*   inv2    = (int*)  alloc((size_t)2*T*4);
  int* counts  = (int*)alloc(E*4);
  int* fill    = (int*)alloc(E*4);
  int* offs    = (int*)alloc((E+2)*4);
  int* nrt     = (int*)alloc(4);
  int* tile_g  = (int*)alloc(MAXRT*4);
  int* tile_r0 = (int*)alloc(MAXRT*4);
  if (off > ws_size) return;   // visible failure if workspace too small

  // y [3T][D] f16 aliases wall: FC (last reader of wall) completes before PROJ writes y.
  unsigned short* y = wall;    // 50 MB needed, 75 MB available

  hipMemsetAsync(counts, 0, E*4, stream);
  hipMemsetAsync(fill,   0, E*4, stream);

  // router + all weight casts in one dispatch
  prep_kernel<<<T/4, 256, 0, stream>>>(
      x, rw, xb, tok_e, tok_w, counts,
      wfc, sfc, wproj, sproj,
      wall, wall + (size_t)E*DFF*D, wpall, wpall + (size_t)E*D*DFF,
      E*DFF*D/4, DFF*D/4, E*D*DFF/4, D*DFF/4);

  scan_kernel   <<<1,   64,  0, stream>>>(counts, offs, tile_g, tile_r0, nrt);
  scatter_kernel<<<RTOT/256, 256, 0, stream>>>(tok_e, tok_w, offs, fill, row_tok, row_w, inv2);

  // FC: h = relu(x @ w_fc^T)^2 for all grouped rows (incl. shared)   [BN=256]
  gemm_fc  <<<dim3(DFF/256, MAXRT), 512, 0, stream>>>(
      xb, wall, h, D, DFF, DFF/256, tile_g, tile_r0, offs, nrt, row_tok);
  // PROJ: y = h @ w_proj^T (raw, unweighted)                          [BN=256]
  gemm_proj<<<dim3(D/256, MAXRT), 512, 0, stream>>>(
      h, wpall, y, DFF, D, D/256, tile_g, tile_r0, offs, nrt, row_tok);
  // combine: weighted sum per token
  combine_kernel<<<(T*128)/256, 256, 0, stream>>>(y, inv2, row_w, out);
}

// Round 15
// 816.200 us; speedup vs baseline: 1.2270x; 1.0300x over previous
//
#include <hip/hip_runtime.h>

#define DEVFN __device__ __forceinline__

typedef _Float16 f16x8 __attribute__((ext_vector_type(8)));
typedef float f32x4 __attribute__((ext_vector_type(4)));

static constexpr int T   = 8192;   // tokens (B*S)
static constexpr int D   = 1024;
static constexpr int E   = 8;
static constexpr int DFF = 4096;
static constexpr int NG  = E + 1;            // 8 experts + shared
static constexpr int RTOT = 3*T;             // 2T routed rows + T shared rows
static constexpr int MAXRT = (2*T)/256 + E + T/256;   // 64 + 8 + 32 = 104 (256-row tiles)

DEVFN unsigned short f2h_bits(float v){
  _Float16 h = (_Float16)v;           // RNE
  return __builtin_bit_cast(unsigned short, h);
}

DEVFN void gload_lds16(const void* g, void* l){
  __builtin_amdgcn_global_load_lds((const __attribute__((address_space(1))) void*)g,
                                   (__attribute__((address_space(3))) void*)l, 16, 0, 0);
}

// ---------------- prep: router (fp32 logits, top-2) + fused weight casts ----------------
__global__ __launch_bounds__(256) void prep_kernel(
    const float* __restrict__ x, const float* __restrict__ rw,
    unsigned short* __restrict__ xb,
    int* __restrict__ tok_e, float* __restrict__ tok_w, int* __restrict__ counts,
    const float* __restrict__ s0, const float* __restrict__ s1,
    const float* __restrict__ s2, const float* __restrict__ s3,
    unsigned short* __restrict__ d0, unsigned short* __restrict__ d1,
    unsigned short* __restrict__ d2, unsigned short* __restrict__ d3,
    int n0, int n1, int n2, int n3){
  // ---- router part ----
  const int lane = threadIdx.x & 63;
  const int t = blockIdx.x*4 + (threadIdx.x >> 6);
  const float4* xp = (const float4*)(x + (size_t)t*D);
  ushort4* xo = (ushort4*)(xb + (size_t)t*D);
  float acc[E];
#pragma unroll
  for (int e=0;e<E;e++) acc[e]=0.f;
#pragma unroll
  for (int i=0;i<4;i++){
    float4 xv = xp[lane + (i<<6)];
    ushort4 o; o.x=f2h_bits(xv.x); o.y=f2h_bits(xv.y); o.z=f2h_bits(xv.z); o.w=f2h_bits(xv.w);
    xo[lane + (i<<6)] = o;
#pragma unroll
    for (int e=0;e<E;e++){
      float4 wv = ((const float4*)(rw + e*D))[lane + (i<<6)];
      acc[e] = fmaf(xv.x,wv.x, fmaf(xv.y,wv.y, fmaf(xv.z,wv.z, fmaf(xv.w,wv.w, acc[e]))));
    }
  }
#pragma unroll
  for (int e=0;e<E;e++){
#pragma unroll
    for (int off=32; off>0; off>>=1) acc[e] += __shfl_xor(acc[e], off);
  }
  if (lane==0){
    float l0=-1e30f, l1=-1e30f; int e0=0, e1=0;
#pragma unroll
    for (int e=0;e<E;e++){
      float v = acc[e];
      if (v > l0){ l1=l0; e1=e0; l0=v; e0=e; }
      else if (v > l1){ l1=v; e1=e; }
    }
    float r   = expf(l1 - l0);          // p1/p0
    float inv = 1.f/(1.f + r);
    tok_e[2*t]   = e0; tok_e[2*t+1] = e1;
    tok_w[2*t]   = inv; tok_w[2*t+1] = r*inv;
    atomicAdd(&counts[e0], 1);
    atomicAdd(&counts[e1], 1);
  }
  // ---- cast part (grid-stride over 4 tensors, float4 units) ----
  int total = n0 + n1 + n2 + n3;
  for (int j = blockIdx.x*256 + threadIdx.x; j < total; j += gridDim.x*256){
    const float* sp; unsigned short* dp; int loc = j;
    if (loc < n0){ sp = s0; dp = d0; }
    else if ((loc -= n0) < n1){ sp = s1; dp = d1; }
    else if ((loc -= n1) < n2){ sp = s2; dp = d2; }
    else { loc -= n2; sp = s3; dp = d3; }
    float4 v = ((const float4*)sp)[loc];
    ushort4 o;
    o.x = f2h_bits(v.x); o.y = f2h_bits(v.y); o.z = f2h_bits(v.z); o.w = f2h_bits(v.w);
    ((ushort4*)dp)[loc] = o;
  }
}

// ---------------- scan: offsets + row-tile map, parallel (1 block, 128 thr) ----------------
__global__ __launch_bounds__(128) void scan_kernel(const int* __restrict__ counts,
    int* __restrict__ offs, int* __restrict__ tile_g, int* __restrict__ tile_r0,
    int* __restrict__ nrt){
  __shared__ int so[NG+1];      // row offsets per group
  __shared__ int tb[NG+1];      // tile-index base per group
  const int tid = threadIdx.x;
  if (tid == 0){
    int off=0, t0=0;
    for (int e=0;e<E;e++){
      so[e]=off; tb[e]=t0;
      offs[e]=off;
      t0  += (counts[e]+255)>>8;
      off += counts[e];
    }
    so[E]=2*T; tb[E]=t0;         // shared group starts at row 2T
    offs[E]   = off;             // == 2T
    offs[E+1] = 3*T;
    tb[NG] = t0 + T/256;
    *nrt = tb[NG];
  }
  __syncthreads();
  const int total = tb[NG];
  for (int i = tid; i < total; i += 128){
    int g = 0;
#pragma unroll
    for (int e=1;e<NG;e++) if (i >= tb[e]) g = e;
    tile_g[i]  = g;
    tile_r0[i] = so[g] + ((i - tb[g]) << 8);
  }
}

// ---------------- scatter: grouped row -> token; inverse map token -> grouped rows ----------------
__global__ __launch_bounds__(256) void scatter_kernel(const int* __restrict__ tok_e,
    const float* __restrict__ tok_w, const int* __restrict__ offs,
    int* __restrict__ fill, int* __restrict__ row_tok, float* __restrict__ row_w,
    int* __restrict__ inv2){
  int idx = blockIdx.x*256 + threadIdx.x;   // [0, 3T)
  if (idx < 2*T){
    int e = tok_e[idx];
    int pos = offs[e] + atomicAdd(&fill[e], 1);
    row_tok[pos] = idx >> 1;
    row_w[pos]   = tok_w[idx];
    inv2[idx]    = pos;                     // inv2[2*token + slot]
  } else {
    row_tok[idx] = idx - 2*T;
    row_w[idx]   = 1.0f;
  }
}

// ---- grouped GEMM, 256x256 tile, BK=64, ring-2 LDS (128 KB), 8-phase schedule with
//      SINGLE barrier per phase: { ds_read frags || stage 1 half-tile [|| counted VMW]
//      -> s_barrier -> 16-MFMA cluster (setprio) }.
//      Hazard ledger (steady state; stage calls: p1 A(kt+1,0), p2 B(kt+1,0), p3 A(kt+1,1),
//      p4 B(kt+1,1), p5 A(kt+2,0), p6 B(kt+2,0), p7 A(kt+2,1), p8 B(kt+2,1); VMW(4) at
//      p2/p4/p6/p8 before the barrier):
//      - reads(buf0-half0)@p1 need A/B(kt,0): retired by prev-p8's VMW(4) (leaves only
//        A/B(kt,1... i.e. kt+1's last half) outstanding) + prev-p8 barrier.  ✓
//      - reads(buf0-half1)@p3 need A/B(kt,1): retired by p2's VMW(4) + p2 barrier. ✓
//      - likewise p5/p7 via p4/p6.  Prologue: 8 loads, VMW(4) retires half0. ✓
//      - WAR: stage(kt+1,h)@p1-p4 overwrites buf1 last READ in prev iteration p5-p8;
//        all waves crossed >=1 barrier (p1's) after those reads' consuming MFMAs. ✓
//      The post-MFMA barrier of r4-r13 protected nothing (MFMA reads registers only);
//      removed: 16 -> 8 barriers per iteration.
// MODE 0: FC (A gathered via row_tok, relu^2 -> h).  MODE 1: PROJ (A contiguous, raw -> y).
template<int MODE>
DEVFN void gemm_core(
    const unsigned short* __restrict__ A, const unsigned short* __restrict__ Ball,
    unsigned short* __restrict__ O,
    const int K, const int N, const int CT,
    const int* __restrict__ tile_g, const int* __restrict__ tile_r0,
    const int* __restrict__ offs, const int* __restrict__ nrt,
    const int* __restrict__ row_tok)
{
  // T1: bijective XCD swizzle on linearized wg id (m204 form)
  const int nwg  = gridDim.x * gridDim.y;
  const int orig = blockIdx.y * gridDim.x + blockIdx.x;
  const int q8 = nwg >> 3, r8 = nwg & 7;
  const int xcd = orig & 7, pos = orig >> 3;
  const int wg = (xcd < r8 ? xcd*(q8+1) : r8*(q8+1) + (xcd-r8)*q8) + pos;
  const int rt = wg / CT, ct = wg - rt*CT;
  if (rt >= *nrt) return;

  const int g    = tile_g[rt];
  const int row0 = tile_r0[rt];
  const int row_end = offs[g+1];
  const unsigned short* Bp = Ball + (size_t)g * (size_t)N * (size_t)K;

  // HT(buf,ks) base = (buf*2+ks)*8192 shorts; each HT = [256 rows][4 x 16B chunks] (k-half)
  __shared__ __align__(16) unsigned short As[2*2*8192];
  __shared__ __align__(16) unsigned short Bs[2*2*8192];

  const int tid  = threadIdx.x;
  const int lane = tid & 63;
  const int wave = tid >> 6;

  // --- staging map: slot s = c*512+tid; row rr = s>>2; local chunk = s&3;
  //     inverse-swizzled global chunk qg = (s&3) ^ ((rr>>1)&3)   (0-conflict, r1-r13)
  const unsigned short* aS[2];
  const unsigned short* bS[2];
  int ldst[2];
#pragma unroll
  for (int c=0;c<2;c++){
    int s  = (c<<9) + tid;
    int rr = s >> 2;
    int qg = (s & 3) ^ ((rr >> 1) & 3);
    int ar = (MODE==0) ? row_tok[row0 + rr] : (row0 + rr);  // row_tok valid on [0,3T)
    aS[c] = A  + (size_t)ar*K + qg*8;
    bS[c] = Bp + (size_t)((ct<<8) + rr)*K + qg*8;
    ldst[c] = ((c<<9) + (wave<<6))*8;        // wave-uniform LDS base (lane*16B implicit)
  }

#define STAGE_A(KT,KS) { _Pragma("unroll") for (int c=0;c<2;c++) \
    gload_lds16(aS[c] + (KT)*64 + (KS)*32, As + ((((KT)&1)*2+(KS))<<13) + ldst[c]); }
#define STAGE_B(KT,KS) { _Pragma("unroll") for (int c=0;c<2;c++) \
    gload_lds16(bS[c] + (KT)*64 + (KS)*32, Bs + ((((KT)&1)*2+(KS))<<13) + ldst[c]); }

  // --- fragment read offsets within a half-tile [256][32] shorts (swizzle matches staging)
  const int wm = wave >> 2, wn = wave & 3;   // 2x4 waves, per-wave output 128 x 64
  const int q16g = lane >> 4;
  int aoff[8], boff[4];
#pragma unroll
  for (int m=0;m<8;m++){
    int r = (wm<<7) + (m<<4) + (lane&15);
    aoff[m] = (r<<5) + ((q16g ^ ((r>>1)&3))<<3);
  }
#pragma unroll
  for (int n=0;n<4;n++){
    int r = (wn<<6) + (n<<4) + (lane&15);
    boff[n] = (r<<5) + ((q16g ^ ((r>>1)&3))<<3);
  }

#define BARS { __builtin_amdgcn_s_barrier(); __builtin_amdgcn_sched_barrier(0); }
#define VMW(NN) asm volatile("s_waitcnt vmcnt(" #NN ")" ::: "memory");
#define DSA(BUF,KS,MQ) { const unsigned short* hb = As + (((BUF)*2+(KS))<<13); \
    _Pragma("unroll") for (int m=0;m<4;m++) af[m] = *(const f16x8*)(hb + aoff[(MQ)*4+m]); }
#define DSB(BUF,KS) { const unsigned short* hb = Bs + (((BUF)*2+(KS))<<13); \
    _Pragma("unroll") for (int n=0;n<4;n++) bf[n] = *(const f16x8*)(hb + boff[n]); }
#define MFMA16(MQ) { __builtin_amdgcn_s_setprio(1); \
    _Pragma("unroll") for (int m=0;m<4;m++) \
    _Pragma("unroll") for (int n=0;n<4;n++) \
      acc[(MQ)*4+m][n] = __builtin_amdgcn_mfma_f32_16x16x32_f16(af[m], bf[n], acc[(MQ)*4+m][n], 0, 0, 0); \
    __builtin_amdgcn_s_setprio(0); }

  f32x4 acc[8][4] = {};
  const int nkt = K >> 6;                    // 64-wide K tiles (16 FC / 64 PROJ)
  const int ni  = nkt >> 1;

  // prologue: stage K-tile 0 (A0,B0,A1,B1 = 8 loads); retire half 0; barrier
  STAGE_A(0,0); STAGE_B(0,0); STAGE_A(0,1); STAGE_B(0,1);
  VMW(4); BARS;

  f16x8 af[4], bf[4];
  for (int i=0;i<ni;++i){
    const int kt = i<<1;
    const bool last = (i == ni-1);
    // ---- K-tile kt (buf0), stage K-tile kt+1 -> buf1
    DSB(0,0); DSA(0,0,0); STAGE_A(kt+1,0);              BARS; MFMA16(0);        // p1
    DSA(0,0,1);           STAGE_B(kt+1,0); VMW(4);      BARS; MFMA16(1);        // p2
    DSB(0,1); DSA(0,1,0); STAGE_A(kt+1,1);              BARS; MFMA16(0);        // p3
    DSA(0,1,1);           STAGE_B(kt+1,1);                                      // p4
    if (last) { VMW(0); } else { VMW(4); }
    BARS; MFMA16(1);
    // ---- K-tile kt+1 (buf1), stage K-tile kt+2 -> buf0
    DSB(1,0); DSA(1,0,0); if (!last) STAGE_A(kt+2,0);   BARS; MFMA16(0);        // p5
    DSA(1,0,1);           if (!last) STAGE_B(kt+2,0);
    VMW(4);                                             BARS; MFMA16(1);        // p6
    DSB(1,1); DSA(1,1,0); if (!last) STAGE_A(kt+2,1);   BARS; MFMA16(0);        // p7
    DSA(1,1,1);           if (!last) STAGE_B(kt+2,1);
    VMW(4);                                             BARS; MFMA16(1);        // p8
  }

  // --- epilogue: C row = (lane>>4)*4 + q, col = lane&15 within each 16x16 fragment
  const int lcol = lane & 15;
  const int lrow = (lane >> 4) << 2;
#pragma unroll
  for (int m=0;m<8;m++){
#pragma unroll
    for (int q=0;q<4;q++){
      const int grow = row0 + (wm<<7) + (m<<4) + lrow + q;
      if (grow >= row_end) continue;           // padded tile rows
#pragma unroll
      for (int n=0;n<4;n++){
        const int col = (ct<<8) + (wn<<6) + (n<<4) + lcol;
        float v = acc[m][n][q];
        if constexpr (MODE==0) v = (v > 0.f) ? v*v : 0.f;   // relu(x)^2
        O[(size_t)grow*N + col] = f2h_bits(v);
      }
    }
  }
#undef STAGE_A
#undef STAGE_B
#undef BARS
#undef VMW
#undef DSA
#undef DSB
#undef MFMA16
}

// distinct symbols so rocprof separates the two GEMMs
__global__ __launch_bounds__(512, 2) void gemm_fc(
    const unsigned short* __restrict__ A, const unsigned short* __restrict__ Ball,
    unsigned short* __restrict__ O, const int K, const int N, const int CT,
    const int* __restrict__ tile_g, const int* __restrict__ tile_r0,
    const int* __restrict__ offs, const int* __restrict__ nrt,
    const int* __restrict__ row_tok){
  gemm_core<0>(A, Ball, O, K, N, CT, tile_g, tile_r0, offs, nrt, row_tok);
}
__global__ __launch_bounds__(512, 2) void gemm_proj(
    const unsigned short* __restrict__ A, const unsigned short* __restrict__ Ball,
    unsigned short* __restrict__ O, const int K, const int N, const int CT,
    const int* __restrict__ tile_g, const int* __restrict__ tile_r0,
    const int* __restrict__ offs, const int* __restrict__ nrt,
    const int* __restrict__ row_tok){
  gemm_core<1>(A, Ball, O, K, N, CT, tile_g, tile_r0, offs, nrt, row_tok);
}

// ---------------- combine: out[t] = w0*y[p0] + w1*y[p1] + y[shared_t] ----------------
__global__ __launch_bounds__(256) void combine_kernel(const unsigned short* __restrict__ y,
    const int* __restrict__ inv2, const float* __restrict__ row_w, float* __restrict__ out){
  int gid = blockIdx.x*256 + threadIdx.x;    // T*128 threads, 8 cols each
  int t = gid >> 7, c = gid & 127;
  int p0 = inv2[2*t], p1 = inv2[2*t+1];
  float w0 = row_w[p0], w1 = row_w[p1];
  f16x8 v0 = *(const f16x8*)(y + (size_t)p0*D      + c*8);
  f16x8 v1 = *(const f16x8*)(y + (size_t)p1*D      + c*8);
  f16x8 v2 = *(const f16x8*)(y + (size_t)(2*T+t)*D + c*8);
  float4 o0, o1;
  float r[8];
#pragma unroll
  for (int j=0;j<8;j++)
    r[j] = fmaf(w0, (float)v0[j], fmaf(w1, (float)v1[j], (float)v2[j]));
  o0.x=r[0]; o0.y=r[1]; o0.z=r[2]; o0.w=r[3];
  o1.x=r[4]; o1.y=r[5]; o1.z=r[6]; o1.w=r[7];
  float4* op = (float4*)(out + (size_t)t*D + c*8);
  op[0] = o0; op[1] = o1;
}

// ---------------- host launcher ----------------
extern "C" void kernel_launch(void* const* d_in, const int* in_sizes, int n_in,
                              void* d_out, int out_size, void* d_ws, size_t ws_size,
                              hipStream_t stream){
  const float* x     = (const float*)d_in[0];
  const float* rw    = (const float*)d_in[1];
  const float* wfc   = (const float*)d_in[2];
  const float* wproj = (const float*)d_in[3];
  const float* sfc   = (const float*)d_in[4];
  const float* sproj = (const float*)d_in[5];
  float* out = (float*)d_out;

  char* ws = (char*)d_ws;
  size_t off = 0;
  auto alloc = [&](size_t bytes)->void*{
    void* p = ws + off; off += (bytes + 255) & ~(size_t)255; return p;
  };
  unsigned short* xb    = (unsigned short*)alloc((size_t)T*D*2);
  unsigned short* wall  = (unsigned short*)alloc((size_t)NG*DFF*D*2);  // experts 0..7 then shared
  unsigned short* wpall = (unsigned short*)alloc((size_t)NG*D*DFF*2);
  unsigned short* h     = (unsigned short*)alloc((size_t)RTOT*DFF*2);
  int*   tok_e   = (int*)  alloc((size_t)T*2*4);
  float* tok_w   = (float*)alloc((size_t)T*2*4);
  int*   row_tok = (int*)  alloc((size_t)RTOT*4);
  float* row_w   = (float*)alloc((size_t)RTOT*4);
  int*   inv2    = (int*)  alloc((size_t)2*T*4);
  int* counts  = (int*)alloc(E*4);
  int* fill    = (int*)alloc(E*4);
  int* offs    = (int*)alloc((E+2)*4);
  int* nrt     = (int*)alloc(4);
  int* tile_g  = (int*)alloc(MAXRT*4);
  int* tile_r0 = (int*)alloc(MAXRT*4);
  if (off > ws_size) return;   // visible failure if workspace too small

  // y [3T][D] f16 aliases wall: FC (last reader of wall) completes before PROJ writes y.
  unsigned short* y = wall;    // 50 MB needed, 75 MB available

  hipMemsetAsync(counts, 0, E*4, stream);
  hipMemsetAsync(fill,   0, E*4, stream);

  // router + all weight casts in one dispatch
  prep_kernel<<<T/4, 256, 0, stream>>>(
      x, rw, xb, tok_e, tok_w, counts,
      wfc, sfc, wproj, sproj,
      wall, wall + (size_t)E*DFF*D, wpall, wpall + (size_t)E*D*DFF,
      E*DFF*D/4, DFF*D/4, E*D*DFF/4, D*DFF/4);

  scan_kernel   <<<1,  128,  0, stream>>>(counts, offs, tile_g, tile_r0, nrt);
  scatter_kernel<<<RTOT/256, 256, 0, stream>>>(tok_e, tok_w, offs, fill, row_tok, row_w, inv2);

  // FC: h = relu(x @ w_fc^T)^2 for all grouped rows (incl. shared)   [BN=256]
  gemm_fc  <<<dim3(DFF/256, MAXRT), 512, 0, stream>>>(
      xb, wall, h, D, DFF, DFF/256, tile_g, tile_r0, offs, nrt, row_tok);
  // PROJ: y = h @ w_proj^T (raw, unweighted)                          [BN=256]
  gemm_proj<<<dim3(D/256, MAXRT), 512, 0, stream>>>(
      h, wpall, y, DFF, D, D/256, tile_g, tile_r0, offs, nrt, row_tok);
  // combine: weighted sum per token
  combine_kernel<<<(T*128)/256, 256, 0, stream>>>(y, inv2, row_w, out);
}

// Round 16
// 793.811 us; speedup vs baseline: 1.2616x; 1.0282x over previous
//
#include <hip/hip_runtime.h>

#define DEVFN __device__ __forceinline__

typedef _Float16 f16x8 __attribute__((ext_vector_type(8)));
typedef float f32x4 __attribute__((ext_vector_type(4)));
typedef float f32x4v __attribute__((ext_vector_type(4)));      // vector fp32x4 (for nt loads)
typedef unsigned short us8 __attribute__((ext_vector_type(8))); // 16B f16 store unit

static constexpr int T   = 8192;   // tokens (B*S)
static constexpr int D   = 1024;
static constexpr int E   = 8;
static constexpr int DFF = 4096;
static constexpr int NG  = E + 1;            // 8 experts + shared
static constexpr int RTOT = 3*T;             // 2T routed rows + T shared rows
static constexpr int MAXRT = (2*T)/256 + E + T/256;   // 64 + 8 + 32 = 104 (256-row tiles)

DEVFN unsigned short f2h_bits(float v){
  _Float16 h = (_Float16)v;           // RNE
  return __builtin_bit_cast(unsigned short, h);
}

DEVFN void gload_lds16(const void* g, void* l){
  __builtin_amdgcn_global_load_lds((const __attribute__((address_space(1))) void*)g,
                                   (__attribute__((address_space(3))) void*)l, 16, 0, 0);
}

// branch-free streaming cast span: 32B nt-load -> 16B store per iteration
DEVFN void cast_span(const float* __restrict__ s, unsigned short* __restrict__ d,
                     int npair, int gtid, int nthr){
  const f32x4v* sp = (const f32x4v*)s;
#pragma unroll 2
  for (int j = gtid; j < npair; j += nthr){
    f32x4v v0 = __builtin_nontemporal_load(sp + 2*j);       // fp32 weights are read once:
    f32x4v v1 = __builtin_nontemporal_load(sp + 2*j + 1);   // keep them out of L2/L3
    us8 o;
    o[0]=f2h_bits(v0[0]); o[1]=f2h_bits(v0[1]); o[2]=f2h_bits(v0[2]); o[3]=f2h_bits(v0[3]);
    o[4]=f2h_bits(v1[0]); o[5]=f2h_bits(v1[1]); o[6]=f2h_bits(v1[2]); o[7]=f2h_bits(v1[3]);
    *(us8*)(d + (size_t)j*8) = o;                            // 16B coalesced store
  }
}

// ---------------- prep: router (fp32 logits, top-2) + fused weight casts ----------------
__global__ __launch_bounds__(256) void prep_kernel(
    const float* __restrict__ x, const float* __restrict__ rw,
    unsigned short* __restrict__ xb,
    int* __restrict__ tok_e, float* __restrict__ tok_w, int* __restrict__ counts,
    const float* __restrict__ s0, const float* __restrict__ s1,
    const float* __restrict__ s2, const float* __restrict__ s3,
    unsigned short* __restrict__ d0, unsigned short* __restrict__ d1,
    unsigned short* __restrict__ d2, unsigned short* __restrict__ d3,
    int p0, int p1, int p2, int p3){            // PAIR counts (2 x float4)
  // ---- router part ----
  const int lane = threadIdx.x & 63;
  const int t = blockIdx.x*4 + (threadIdx.x >> 6);
  const float4* xp = (const float4*)(x + (size_t)t*D);
  ushort4* xo = (ushort4*)(xb + (size_t)t*D);
  float acc[E];
#pragma unroll
  for (int e=0;e<E;e++) acc[e]=0.f;
#pragma unroll
  for (int i=0;i<4;i++){
    float4 xv = xp[lane + (i<<6)];
    ushort4 o; o.x=f2h_bits(xv.x); o.y=f2h_bits(xv.y); o.z=f2h_bits(xv.z); o.w=f2h_bits(xv.w);
    xo[lane + (i<<6)] = o;
#pragma unroll
    for (int e=0;e<E;e++){
      float4 wv = ((const float4*)(rw + e*D))[lane + (i<<6)];
      acc[e] = fmaf(xv.x,wv.x, fmaf(xv.y,wv.y, fmaf(xv.z,wv.z, fmaf(xv.w,wv.w, acc[e]))));
    }
  }
#pragma unroll
  for (int e=0;e<E;e++){
#pragma unroll
    for (int off=32; off>0; off>>=1) acc[e] += __shfl_xor(acc[e], off);
  }
  if (lane==0){
    float l0=-1e30f, l1=-1e30f; int e0=0, e1=0;
#pragma unroll
    for (int e=0;e<E;e++){
      float v = acc[e];
      if (v > l0){ l1=l0; e1=e0; l0=v; e0=e; }
      else if (v > l1){ l1=v; e1=e; }
    }
    float r   = expf(l1 - l0);          // p1/p0
    float inv = 1.f/(1.f + r);
    tok_e[2*t]   = e0; tok_e[2*t+1] = e1;
    tok_w[2*t]   = inv; tok_w[2*t+1] = r*inv;
    atomicAdd(&counts[e0], 1);
    atomicAdd(&counts[e1], 1);
  }
  // ---- cast part: 4 branch-free spans, 32B read / 16B write per lane-iter ----
  const int gtid = blockIdx.x*256 + threadIdx.x;
  const int nthr = gridDim.x*256;
  cast_span(s0, d0, p0, gtid, nthr);
  cast_span(s1, d1, p1, gtid, nthr);
  cast_span(s2, d2, p2, gtid, nthr);
  cast_span(s3, d3, p3, gtid, nthr);
}

// ---------------- scan: offsets + row-tile map, parallel (1 block, 128 thr) ----------------
__global__ __launch_bounds__(128) void scan_kernel(const int* __restrict__ counts,
    int* __restrict__ offs, int* __restrict__ tile_g, int* __restrict__ tile_r0,
    int* __restrict__ nrt){
  __shared__ int so[NG+1];      // row offsets per group
  __shared__ int tb[NG+1];      // tile-index base per group
  const int tid = threadIdx.x;
  if (tid == 0){
    int off=0, t0=0;
    for (int e=0;e<E;e++){
      so[e]=off; tb[e]=t0;
      offs[e]=off;
      t0  += (counts[e]+255)>>8;
      off += counts[e];
    }
    so[E]=2*T; tb[E]=t0;         // shared group starts at row 2T
    offs[E]   = off;             // == 2T
    offs[E+1] = 3*T;
    tb[NG] = t0 + T/256;
    *nrt = tb[NG];
  }
  __syncthreads();
  const int total = tb[NG];
  for (int i = tid; i < total; i += 128){
    int g = 0;
#pragma unroll
    for (int e=1;e<NG;e++) if (i >= tb[e]) g = e;
    tile_g[i]  = g;
    tile_r0[i] = so[g] + ((i - tb[g]) << 8);
  }
}

// ---------------- scatter: grouped row -> token; inverse map token -> grouped rows ----------------
__global__ __launch_bounds__(256) void scatter_kernel(const int* __restrict__ tok_e,
    const float* __restrict__ tok_w, const int* __restrict__ offs,
    int* __restrict__ fill, int* __restrict__ row_tok, float* __restrict__ row_w,
    int* __restrict__ inv2){
  int idx = blockIdx.x*256 + threadIdx.x;   // [0, 3T)
  if (idx < 2*T){
    int e = tok_e[idx];
    int pos = offs[e] + atomicAdd(&fill[e], 1);
    row_tok[pos] = idx >> 1;
    row_w[pos]   = tok_w[idx];
    inv2[idx]    = pos;                     // inv2[2*token + slot]
  } else {
    row_tok[idx] = idx - 2*T;
    row_w[idx]   = 1.0f;
  }
}

// ---- grouped GEMM, 256x256 tile, BK=64, ring-2 LDS (128 KB), 8-phase schedule,
//      SINGLE barrier per phase (r14-verified): { ds_read frags || stage 1 half-tile
//      [|| counted VMW] -> s_barrier -> 16-MFMA cluster (setprio) }.
//      Hazard ledger: see r14 notes — counted VMW(4)+barrier one phase before each read;
//      WAR targets last read >=1 barrier earlier; only last K-tile drains vmcnt(0).
// MODE 0: FC (A gathered via row_tok, relu^2 -> h).  MODE 1: PROJ (A contiguous, raw -> y).
template<int MODE>
DEVFN void gemm_core(
    const unsigned short* __restrict__ A, const unsigned short* __restrict__ Ball,
    unsigned short* __restrict__ O,
    const int K, const int N, const int CT,
    const int* __restrict__ tile_g, const int* __restrict__ tile_r0,
    const int* __restrict__ offs, const int* __restrict__ nrt,
    const int* __restrict__ row_tok)
{
  // T1: bijective XCD swizzle on linearized wg id (m204 form)
  const int nwg  = gridDim.x * gridDim.y;
  const int orig = blockIdx.y * gridDim.x + blockIdx.x;
  const int q8 = nwg >> 3, r8 = nwg & 7;
  const int xcd = orig & 7, pos = orig >> 3;
  const int wg = (xcd < r8 ? xcd*(q8+1) : r8*(q8+1) + (xcd-r8)*q8) + pos;
  const int rt = wg / CT, ct = wg - rt*CT;
  if (rt >= *nrt) return;

  const int g    = tile_g[rt];
  const int row0 = tile_r0[rt];
  const int row_end = offs[g+1];
  const unsigned short* Bp = Ball + (size_t)g * (size_t)N * (size_t)K;

  // HT(buf,ks) base = (buf*2+ks)*8192 shorts; each HT = [256 rows][4 x 16B chunks] (k-half)
  __shared__ __align__(16) unsigned short As[2*2*8192];
  __shared__ __align__(16) unsigned short Bs[2*2*8192];

  const int tid  = threadIdx.x;
  const int lane = tid & 63;
  const int wave = tid >> 6;

  // --- staging map: slot s = c*512+tid; row rr = s>>2; local chunk = s&3;
  //     inverse-swizzled global chunk qg = (s&3) ^ ((rr>>1)&3)   (0-conflict, r1-r14)
  const unsigned short* aS[2];
  const unsigned short* bS[2];
  int ldst[2];
#pragma unroll
  for (int c=0;c<2;c++){
    int s  = (c<<9) + tid;
    int rr = s >> 2;
    int qg = (s & 3) ^ ((rr >> 1) & 3);
    int ar = (MODE==0) ? row_tok[row0 + rr] : (row0 + rr);  // row_tok valid on [0,3T)
    aS[c] = A  + (size_t)ar*K + qg*8;
    bS[c] = Bp + (size_t)((ct<<8) + rr)*K + qg*8;
    ldst[c] = ((c<<9) + (wave<<6))*8;        // wave-uniform LDS base (lane*16B implicit)
  }

#define STAGE_A(KT,KS) { _Pragma("unroll") for (int c=0;c<2;c++) \
    gload_lds16(aS[c] + (KT)*64 + (KS)*32, As + ((((KT)&1)*2+(KS))<<13) + ldst[c]); }
#define STAGE_B(KT,KS) { _Pragma("unroll") for (int c=0;c<2;c++) \
    gload_lds16(bS[c] + (KT)*64 + (KS)*32, Bs + ((((KT)&1)*2+(KS))<<13) + ldst[c]); }

  // --- fragment read offsets within a half-tile [256][32] shorts (swizzle matches staging)
  const int wm = wave >> 2, wn = wave & 3;   // 2x4 waves, per-wave output 128 x 64
  const int q16g = lane >> 4;
  int aoff[8], boff[4];
#pragma unroll
  for (int m=0;m<8;m++){
    int r = (wm<<7) + (m<<4) + (lane&15);
    aoff[m] = (r<<5) + ((q16g ^ ((r>>1)&3))<<3);
  }
#pragma unroll
  for (int n=0;n<4;n++){
    int r = (wn<<6) + (n<<4) + (lane&15);
    boff[n] = (r<<5) + ((q16g ^ ((r>>1)&3))<<3);
  }

#define BARS { __builtin_amdgcn_s_barrier(); __builtin_amdgcn_sched_barrier(0); }
#define VMW(NN) asm volatile("s_waitcnt vmcnt(" #NN ")" ::: "memory");
#define DSA(BUF,KS,MQ) { const unsigned short* hb = As + (((BUF)*2+(KS))<<13); \
    _Pragma("unroll") for (int m=0;m<4;m++) af[m] = *(const f16x8*)(hb + aoff[(MQ)*4+m]); }
#define DSB(BUF,KS) { const unsigned short* hb = Bs + (((BUF)*2+(KS))<<13); \
    _Pragma("unroll") for (int n=0;n<4;n++) bf[n] = *(const f16x8*)(hb + boff[n]); }
#define MFMA16(MQ) { __builtin_amdgcn_s_setprio(1); \
    _Pragma("unroll") for (int m=0;m<4;m++) \
    _Pragma("unroll") for (int n=0;n<4;n++) \
      acc[(MQ)*4+m][n] = __builtin_amdgcn_mfma_f32_16x16x32_f16(af[m], bf[n], acc[(MQ)*4+m][n], 0, 0, 0); \
    __builtin_amdgcn_s_setprio(0); }

  f32x4 acc[8][4] = {};
  const int nkt = K >> 6;                    // 64-wide K tiles (16 FC / 64 PROJ)
  const int ni  = nkt >> 1;

  // prologue: stage K-tile 0 (A0,B0,A1,B1 = 8 loads); retire half 0; barrier
  STAGE_A(0,0); STAGE_B(0,0); STAGE_A(0,1); STAGE_B(0,1);
  VMW(4); BARS;

  f16x8 af[4], bf[4];
  for (int i=0;i<ni;++i){
    const int kt = i<<1;
    const bool last = (i == ni-1);
    // ---- K-tile kt (buf0), stage K-tile kt+1 -> buf1
    DSB(0,0); DSA(0,0,0); STAGE_A(kt+1,0);              BARS; MFMA16(0);        // p1
    DSA(0,0,1);           STAGE_B(kt+1,0); VMW(4);      BARS; MFMA16(1);        // p2
    DSB(0,1); DSA(0,1,0); STAGE_A(kt+1,1);              BARS; MFMA16(0);        // p3
    DSA(0,1,1);           STAGE_B(kt+1,1);                                      // p4
    if (last) { VMW(0); } else { VMW(4); }
    BARS; MFMA16(1);
    // ---- K-tile kt+1 (buf1), stage K-tile kt+2 -> buf0
    DSB(1,0); DSA(1,0,0); if (!last) STAGE_A(kt+2,0);   BARS; MFMA16(0);        // p5
    DSA(1,0,1);           if (!last) STAGE_B(kt+2,0);
    VMW(4);                                             BARS; MFMA16(1);        // p6
    DSB(1,1); DSA(1,1,0); if (!last) STAGE_A(kt+2,1);   BARS; MFMA16(0);        // p7
    DSA(1,1,1);           if (!last) STAGE_B(kt+2,1);
    VMW(4);                                             BARS; MFMA16(1);        // p8
  }

  // --- epilogue: C row = (lane>>4)*4 + q, col = lane&15 within each 16x16 fragment
  const int lcol = lane & 15;
  const int lrow = (lane >> 4) << 2;
#pragma unroll
  for (int m=0;m<8;m++){
#pragma unroll
    for (int q=0;q<4;q++){
      const int grow = row0 + (wm<<7) + (m<<4) + lrow + q;
      if (grow >= row_end) continue;           // padded tile rows
#pragma unroll
      for (int n=0;n<4;n++){
        const int col = (ct<<8) + (wn<<6) + (n<<4) + lcol;
        float v = acc[m][n][q];
        if constexpr (MODE==0) v = (v > 0.f) ? v*v : 0.f;   // relu(x)^2
        O[(size_t)grow*N + col] = f2h_bits(v);
      }
    }
  }
#undef STAGE_A
#undef STAGE_B
#undef BARS
#undef VMW
#undef DSA
#undef DSB
#undef MFMA16
}

// distinct symbols so rocprof separates the two GEMMs
__global__ __launch_bounds__(512, 2) void gemm_fc(
    const unsigned short* __restrict__ A, const unsigned short* __restrict__ Ball,
    unsigned short* __restrict__ O, const int K, const int N, const int CT,
    const int* __restrict__ tile_g, const int* __restrict__ tile_r0,
    const int* __restrict__ offs, const int* __restrict__ nrt,
    const int* __restrict__ row_tok){
  gemm_core<0>(A, Ball, O, K, N, CT, tile_g, tile_r0, offs, nrt, row_tok);
}
__global__ __launch_bounds__(512, 2) void gemm_proj(
    const unsigned short* __restrict__ A, const unsigned short* __restrict__ Ball,
    unsigned short* __restrict__ O, const int K, const int N, const int CT,
    const int* __restrict__ tile_g, const int* __restrict__ tile_r0,
    const int* __restrict__ offs, const int* __restrict__ nrt,
    const int* __restrict__ row_tok){
  gemm_core<1>(A, Ball, O, K, N, CT, tile_g, tile_r0, offs, nrt, row_tok);
}

// ---------------- combine: out[t] = w0*y[p0] + w1*y[p1] + y[shared_t] ----------------
__global__ __launch_bounds__(256) void combine_kernel(const unsigned short* __restrict__ y,
    const int* __restrict__ inv2, const float* __restrict__ row_w, float* __restrict__ out){
  int gid = blockIdx.x*256 + threadIdx.x;    // T*128 threads, 8 cols each
  int t = gid >> 7, c = gid & 127;
  int p0 = inv2[2*t], p1 = inv2[2*t+1];
  float w0 = row_w[p0], w1 = row_w[p1];
  f16x8 v0 = *(const f16x8*)(y + (size_t)p0*D      + c*8);
  f16x8 v1 = *(const f16x8*)(y + (size_t)p1*D      + c*8);
  f16x8 v2 = *(const f16x8*)(y + (size_t)(2*T+t)*D + c*8);
  float4 o0, o1;
  float r[8];
#pragma unroll
  for (int j=0;j<8;j++)
    r[j] = fmaf(w0, (float)v0[j], fmaf(w1, (float)v1[j], (float)v2[j]));
  o0.x=r[0]; o0.y=r[1]; o0.z=r[2]; o0.w=r[3];
  o1.x=r[4]; o1.y=r[5]; o1.z=r[6]; o1.w=r[7];
  float4* op = (float4*)(out + (size_t)t*D + c*8);
  op[0] = o0; op[1] = o1;
}

// ---------------- host launcher ----------------
extern "C" void kernel_launch(void* const* d_in, const int* in_sizes, int n_in,
                              void* d_out, int out_size, void* d_ws, size_t ws_size,
                              hipStream_t stream){
  const float* x     = (const float*)d_in[0];
  const float* rw    = (const float*)d_in[1];
  const float* wfc   = (const float*)d_in[2];
  const float* wproj = (const float*)d_in[3];
  const float* sfc   = (const float*)d_in[4];
  const float* sproj = (const float*)d_in[5];
  float* out = (float*)d_out;

  char* ws = (char*)d_ws;
  size_t off = 0;
  auto alloc = [&](size_t bytes)->void*{
    void* p = ws + off; off += (bytes + 255) & ~(size_t)255; return p;
  };
  unsigned short* xb    = (unsigned short*)alloc((size_t)T*D*2);
  unsigned short* wall  = (unsigned short*)alloc((size_t)NG*DFF*D*2);  // experts 0..7 then shared
  unsigned short* wpall = (unsigned short*)alloc((size_t)NG*D*DFF*2);
  unsigned short* h     = (unsigned short*)alloc((size_t)RTOT*DFF*2);
  int*   tok_e   = (int*)  alloc((size_t)T*2*4);
  float* tok_w   = (float*)alloc((size_t)T*2*4);
  int*   row_tok = (int*)  alloc((size_t)RTOT*4);
  float* row_w   = (float*)alloc((size_t)RTOT*4);
  int*   inv2    = (int*)  alloc((size_t)2*T*4);
  int* counts  = (int*)alloc(E*4);
  int* fill    = (int*)alloc(E*4);
  int* offs    = (int*)alloc((E+2)*4);
  int* nrt     = (int*)alloc(4);
  int* tile_g  = (int*)alloc(MAXRT*4);
  int* tile_r0 = (int*)alloc(MAXRT*4);
  if (off > ws_size) return;   // visible failure if workspace too small

  // y [3T][D] f16 aliases wall: FC (last reader of wall) completes before PROJ writes y.
  unsigned short* y = wall;    // 50 MB needed, 75 MB available

  hipMemsetAsync(counts, 0, E*4, stream);
  hipMemsetAsync(fill,   0, E*4, stream);

  // router + all weight casts in one dispatch (pair counts = float4 count / 2)
  prep_kernel<<<T/4, 256, 0, stream>>>(
      x, rw, xb, tok_e, tok_w, counts,
      wfc, sfc, wproj, sproj,
      wall, wall + (size_t)E*DFF*D, wpall, wpall + (size_t)E*D*DFF,
      E*DFF*D/8, DFF*D/8, E*D*DFF/8, D*DFF/8);

  scan_kernel   <<<1,  128,  0, stream>>>(counts, offs, tile_g, tile_r0, nrt);
  scatter_kernel<<<RTOT/256, 256, 0, stream>>>(tok_e, tok_w, offs, fill, row_tok, row_w, inv2);

  // FC: h = relu(x @ w_fc^T)^2 for all grouped rows (incl. shared)   [BN=256]
  gemm_fc  <<<dim3(DFF/256, MAXRT), 512, 0, stream>>>(
      xb, wall, h, D, DFF, DFF/256, tile_g, tile_r0, offs, nrt, row_tok);
  // PROJ: y = h @ w_proj^T (raw, unweighted)                          [BN=256]
  gemm_proj<<<dim3(D/256, MAXRT), 512, 0, stream>>>(
      h, wpall, y, DFF, D, D/256, tile_g, tile_r0, offs, nrt, row_tok);
  // combine: weighted sum per token
  combine_kernel<<<(T*128)/256, 256, 0, stream>>>(y, inv2, row_w, out);
}